// Round 6
// baseline (122.016 us; speedup 1.0000x reference)
//
#include <hip/hip_runtime.h>

#define TOPK 10
#define BLK 256
#define ROWS_SAMPLE 8
#define ROWS_MAIN 16
#define CAND_CAP 32768
#define SLACK 2e-5f
#define NSLOTS 10

typedef float f4vec __attribute__((ext_vector_type(4)));

__device__ __forceinline__ bool better(float v1, int i1, float v2, int i2) {
    // top_k order: larger value first; ties broken by smaller flat index
    return (v1 > v2) || (v1 == v2 && i1 < i2);
}

__device__ __forceinline__ void insert10(float (&lv)[TOPK], int (&li)[TOPK],
                                         float v, int ix, float& mv, int& mi) {
    int ws = 0; float wv = lv[0]; int wi = li[0];
#pragma unroll
    for (int j = 1; j < TOPK; ++j)
        if (better(wv, wi, lv[j], li[j])) { wv = lv[j]; wi = li[j]; ws = j; }
#pragma unroll
    for (int j = 0; j < TOPK; ++j)
        if (j == ws) { lv[j] = v; li[j] = ix; }
    mv = lv[0]; mi = li[0];
#pragma unroll
    for (int j = 1; j < TOPK; ++j)
        if (better(mv, mi, lv[j], li[j])) { mv = lv[j]; mi = li[j]; }
}

__device__ __forceinline__ void waveReduceTop10(float (&lv)[TOPK], int (&li)[TOPK],
                                                float* wcv, int* wci, int tid) {
    const int wave = tid >> 6;
    const int lane = tid & 63;
    for (int r = 0; r < TOPK; ++r) {
        float bv = lv[0]; int bi = li[0];
#pragma unroll
        for (int j = 1; j < TOPK; ++j)
            if (better(lv[j], li[j], bv, bi)) { bv = lv[j]; bi = li[j]; }
#pragma unroll
        for (int off = 32; off >= 1; off >>= 1) {
            float ov = __shfl_xor(bv, off, 64);
            int   oi = __shfl_xor(bi, off, 64);
            if (better(ov, oi, bv, bi)) { bv = ov; bi = oi; }
        }
#pragma unroll
        for (int j = 0; j < TOPK; ++j)
            if (lv[j] == bv && li[j] == bi) { lv[j] = -2.0f; li[j] = 0x7fffffff; }
        if (lane == 0) { wcv[wave * TOPK + r] = bv; wci[wave * TOPK + r] = bi; }
    }
}

template <typename EmitFn>
__device__ __forceinline__ void wave0FinalTop10(const float* wcv, const int* wci,
                                                int tid, EmitFn emit) {
    float v = (tid < 40) ? wcv[tid] : -2.0f;
    int   ix = (tid < 40) ? wci[tid] : 0x7fffffff;
    for (int r = 0; r < TOPK; ++r) {
        float bv = v; int bi = ix;
#pragma unroll
        for (int off = 32; off >= 1; off >>= 1) {
            float ov = __shfl_xor(bv, off, 64);
            int   oi = __shfl_xor(bi, off, 64);
            if (better(ov, oi, bv, bi)) { bv = ov; bi = oi; }
        }
        if (v == bv && ix == bi) { v = -2.0f; ix = 0x7fffffff; }
        if (tid == 0) emit(r, bv, bi);
    }
}

// Exact IoU: bitwise-matches the numpy reference (verified absmax 0.0 in
// rounds 1-3). No FMA contraction (__fmul_rn), IEEE f32 divide. Used ONLY
// for candidate re-ranking (selection must be exact).
__device__ __forceinline__ float iou_exact(const float4 a, const float aA,
                                           const float4 b, const float bA) {
    const float ltx = fmaxf(a.x, b.x);
    const float lty = fmaxf(a.y, b.y);
    const float rbx = fminf(a.z, b.z);
    const float rby = fminf(a.w, b.w);
    const float w = fmaxf(rbx - ltx, 0.0f);
    const float h = fmaxf(rby - lty, 0.0f);
    const float inter = __fmul_rn(w, h);
    const float s = aA + bA;
    const float uni = s - inter;
    const float den = uni + 1e-8f;
    return inter / den;
}

// Fast IoU: v_rcp_f32 (rel err ~1e-7). Stored values only need the 2e-2
// harness tolerance; selection is re-derived exactly in K4; SLACK=2e-5
// covers all fast-vs-exact discrepancies in the threshold chain.
__device__ __forceinline__ float iou_fast(const float4 a, const float aA,
                                          const float4 b, const float bA) {
    const float ltx = fmaxf(a.x, b.x);
    const float lty = fmaxf(a.y, b.y);
    const float rbx = fminf(a.z, b.z);
    const float rby = fminf(a.w, b.w);
    const float w = fmaxf(rbx - ltx, 0.0f);
    const float h = fmaxf(rby - lty, 0.0f);
    const float inter = w * h;
    const float den = (aA + bA - inter) + 1e-8f;
    return inter * __builtin_amdgcn_rcpf(den);
}

// K0: sampled slot-max sketch. Each block: max of 256 fast-IoU samples ->
// atomicMax into slots[bid % 10]. Tm = min(slots) - SLACK is a valid lower
// bound on the global 10th-largest: the 10 slot maxima are 10 DISTINCT
// elements (disjoint block partitions), and min of any 10 distinct elements
// <= 10th-largest. Slots are pre-zeroed via hipMemsetAsync (IoU >= 0, so
// float bits are monotonic under unsigned max).
__global__ __launch_bounds__(BLK) void sample_max_kernel(
    const float4* __restrict__ prop, const float4* __restrict__ gt,
    unsigned int* __restrict__ slots, int N, int M) {
    const int tid = threadIdx.x;
    const int bid = blockIdx.x;
    const int row = bid * ROWS_SAMPLE + (tid & 7);
    long long c = ((long long)(tid >> 3) * M) >> 5;
    const int col = (int)((c + (bid & 63)) % M);

    float v = 0.0f;
    if (row < N) {
        const float4 a = prop[row];
        const float aA = (a.z - a.x) * (a.w - a.y);
        const float4 b = gt[col];
        const float bA = (b.z - b.x) * (b.w - b.y);
        v = iou_fast(a, aA, b, bA);
    }

    __shared__ float sred[4];
#pragma unroll
    for (int off = 32; off >= 1; off >>= 1)
        v = fmaxf(v, __shfl_xor(v, off, 64));
    if ((tid & 63) == 0) sred[tid >> 6] = v;
    __syncthreads();
    if (tid == 0) {
        const float bm = fmaxf(fmaxf(sred[0], sred[1]), fmaxf(sred[2], sred[3]));
        atomicMax(&slots[bid % NSLOTS], __float_as_uint(bm));
    }
}

// K1a: iou-only compute+store pass. Each block owns 16 rows; each thread
// owns 4 consecutive columns per tile (held in registers, reused across all
// 16 rows). One contiguous float4 store per (row, tile). No mask writes.
__global__ __launch_bounds__(BLK) void iou_main_kernel(
    const float4* __restrict__ prop, const float4* __restrict__ gt,
    float* __restrict__ iou_out,
    const unsigned int* __restrict__ slots, int* __restrict__ cand_cnt,
    int* __restrict__ cand_idx, int N, int M) {
    const int tid = threadIdx.x;
    const int bid = blockIdx.x;
    const int row0 = bid * ROWS_MAIN;

    // threshold from the 10 slot maxima
    unsigned int mn = slots[0];
#pragma unroll
    for (int s = 1; s < NSLOTS; ++s) mn = min(mn, slots[s]);
    const float Tm = __uint_as_float(mn) - SLACK;

    // hoist the block's proposal rows (block-uniform addresses -> SGPR)
    float4 pa[ROWS_MAIN];
    float  paA[ROWS_MAIN];
#pragma unroll
    for (int nl = 0; nl < ROWS_MAIN; ++nl) {
        const int r = row0 + nl;
        const float4 a = (r < N) ? prop[r] : make_float4(0.f, 0.f, 0.f, 0.f);
        pa[nl] = a;
        paA[nl] = (a.z - a.x) * (a.w - a.y);
    }

    for (int c0 = 4 * tid; c0 < M; c0 += 4 * BLK) {   // M % 4 == 0
        const float4 b0 = gt[c0 + 0], b1 = gt[c0 + 1], b2 = gt[c0 + 2], b3 = gt[c0 + 3];
        const float bA0 = (b0.z - b0.x) * (b0.w - b0.y);
        const float bA1 = (b1.z - b1.x) * (b1.w - b1.y);
        const float bA2 = (b2.z - b2.x) * (b2.w - b2.y);
        const float bA3 = (b3.z - b3.x) * (b3.w - b3.y);
#pragma unroll
        for (int nl = 0; nl < ROWS_MAIN; ++nl) {
            const int row = row0 + nl;
            if (row < N) {
                const float i0 = iou_fast(pa[nl], paA[nl], b0, bA0);
                const float i1 = iou_fast(pa[nl], paA[nl], b1, bA1);
                const float i2 = iou_fast(pa[nl], paA[nl], b2, bA2);
                const float i3 = iou_fast(pa[nl], paA[nl], b3, bA3);
                const long long base = (long long)row * M + c0;
                const f4vec iv = {i0, i1, i2, i3};
                *reinterpret_cast<f4vec*>(iou_out + base) = iv;
                const float mx = fmaxf(fmaxf(i0, i1), fmaxf(i2, i3));
                if (mx >= Tm) {                        // rare
                    if (i0 >= Tm) { int s = atomicAdd(cand_cnt, 1); if (s < CAND_CAP) cand_idx[s] = (int)base; }
                    if (i1 >= Tm) { int s = atomicAdd(cand_cnt, 1); if (s < CAND_CAP) cand_idx[s] = (int)base + 1; }
                    if (i2 >= Tm) { int s = atomicAdd(cand_cnt, 1); if (s < CAND_CAP) cand_idx[s] = (int)base + 2; }
                    if (i3 >= Tm) { int s = atomicAdd(cand_cnt, 1); if (s < CAND_CAP) cand_idx[s] = (int)base + 3; }
                }
            }
        }
    }
}

// K2: pure mask zero-fill, structurally identical to fillBufferAligned.
__global__ __launch_bounds__(BLK) void mask_fill_kernel(
    float* __restrict__ mask_out, long long n4) {
    const f4vec zero4 = {0.0f, 0.0f, 0.0f, 0.0f};
    const long long stride = (long long)gridDim.x * BLK;
    for (long long i = (long long)blockIdx.x * BLK + threadIdx.x; i < n4; i += stride)
        *((f4vec*)mask_out + i) = zero4;
}

// K4: recompute EXACT IoU for each candidate from the raw boxes, rank by
// (exact value desc, index asc) — bitwise-identical selection to the
// reference regardless of what K1a stored. Scatter ones into mask.
__global__ __launch_bounds__(BLK) void final_kernel(
    const float4* __restrict__ prop, const float4* __restrict__ gt,
    const int* __restrict__ cand_cnt, const int* __restrict__ cand_idx,
    float* __restrict__ mask_out, int M) {
    __shared__ float wcv[4 * TOPK];
    __shared__ int   wci[4 * TOPK];
    const int tid = threadIdx.x;
    int c = *cand_cnt;
    if (c > CAND_CAP) c = CAND_CAP;

    float lv[TOPK]; int li[TOPK];
#pragma unroll
    for (int j = 0; j < TOPK; ++j) { lv[j] = -2.0f; li[j] = 0x7fffffff; }
    float mv = -2.0f; int mi = 0x7fffffff;

    for (int i = tid; i < c; i += BLK) {
        const int idx = cand_idx[i];
        const int row = idx / M;
        const int col = idx - row * M;
        const float4 a = prop[row];
        const float4 b = gt[col];
        const float aA = __fmul_rn(a.z - a.x, a.w - a.y);
        const float bA = __fmul_rn(b.z - b.x, b.w - b.y);
        const float v = iou_exact(a, aA, b, bA);
        if (better(v, idx, mv, mi)) insert10(lv, li, v, idx, mv, mi);
    }
    waveReduceTop10(lv, li, wcv, wci, tid);
    __syncthreads();
    if (tid < 64) {
        wave0FinalTop10(wcv, wci, tid, [&](int r, float bv, int bi) {
            (void)r;
            if (bi >= 0 && bi != 0x7fffffff && bv >= 0.0f) mask_out[bi] = 1.0f;
        });
    }
}

extern "C" void kernel_launch(void* const* d_in, const int* in_sizes, int n_in,
                              void* d_out, int out_size, void* d_ws, size_t ws_size,
                              hipStream_t stream) {
    const float4* prop = (const float4*)d_in[0];
    // d_in[1] = cls_prob (unused), d_in[3] = gt_cls (unused)
    const float4* gt = (const float4*)d_in[2];
    const int N = in_sizes[0] / 4;
    const int M = in_sizes[2] / 4;

    float* iou_out = (float*)d_out;
    float* mask_out = iou_out + (long long)N * M;

    // ws layout: slots[10] u32 @0 | cand_cnt @40 | cand_idx @64
    char* ws = (char*)d_ws;
    unsigned int* slots = (unsigned int*)ws;
    int* cand_cnt = (int*)(ws + 40);
    int* cand_idx = (int*)(ws + 64);

    hipMemsetAsync(ws, 0, 44, stream);   // zero slots + cand_cnt

    const int nb_sample = (N + ROWS_SAMPLE - 1) / ROWS_SAMPLE;
    const int nb_main = (N + ROWS_MAIN - 1) / ROWS_MAIN;
    const long long n4 = ((long long)N * M) >> 2;

    sample_max_kernel<<<nb_sample, BLK, 0, stream>>>(prop, gt, slots, N, M);
    iou_main_kernel<<<nb_main, BLK, 0, stream>>>(prop, gt, iou_out, slots,
                                                 cand_cnt, cand_idx, N, M);
    mask_fill_kernel<<<2048, BLK, 0, stream>>>(mask_out, n4);
    final_kernel<<<1, BLK, 0, stream>>>(prop, gt, cand_cnt, cand_idx, mask_out, M);
}

// Round 7
// 104.342 us; speedup vs baseline: 1.1694x; 1.1694x over previous
//
#include <hip/hip_runtime.h>

#define TOPK 10
#define BLK 256
#define ROWS_PER_BLOCK 8
#define CAND_CAP 32768
#define SLACK 2e-5f
#define NSLOTS 10

typedef float f4vec __attribute__((ext_vector_type(4)));

__device__ __forceinline__ bool better(float v1, int i1, float v2, int i2) {
    // top_k order: larger value first; ties broken by smaller flat index
    return (v1 > v2) || (v1 == v2 && i1 < i2);
}

__device__ __forceinline__ void insert10(float (&lv)[TOPK], int (&li)[TOPK],
                                         float v, int ix, float& mv, int& mi) {
    int ws = 0; float wv = lv[0]; int wi = li[0];
#pragma unroll
    for (int j = 1; j < TOPK; ++j)
        if (better(wv, wi, lv[j], li[j])) { wv = lv[j]; wi = li[j]; ws = j; }
#pragma unroll
    for (int j = 0; j < TOPK; ++j)
        if (j == ws) { lv[j] = v; li[j] = ix; }
    mv = lv[0]; mi = li[0];
#pragma unroll
    for (int j = 1; j < TOPK; ++j)
        if (better(mv, mi, lv[j], li[j])) { mv = lv[j]; mi = li[j]; }
}

__device__ __forceinline__ void waveReduceTop10(float (&lv)[TOPK], int (&li)[TOPK],
                                                float* wcv, int* wci, int tid) {
    const int wave = tid >> 6;
    const int lane = tid & 63;
    for (int r = 0; r < TOPK; ++r) {
        float bv = lv[0]; int bi = li[0];
#pragma unroll
        for (int j = 1; j < TOPK; ++j)
            if (better(lv[j], li[j], bv, bi)) { bv = lv[j]; bi = li[j]; }
#pragma unroll
        for (int off = 32; off >= 1; off >>= 1) {
            float ov = __shfl_xor(bv, off, 64);
            int   oi = __shfl_xor(bi, off, 64);
            if (better(ov, oi, bv, bi)) { bv = ov; bi = oi; }
        }
#pragma unroll
        for (int j = 0; j < TOPK; ++j)
            if (lv[j] == bv && li[j] == bi) { lv[j] = -2.0f; li[j] = 0x7fffffff; }
        if (lane == 0) { wcv[wave * TOPK + r] = bv; wci[wave * TOPK + r] = bi; }
    }
}

template <typename EmitFn>
__device__ __forceinline__ void wave0FinalTop10(const float* wcv, const int* wci,
                                                int tid, EmitFn emit) {
    float v = (tid < 40) ? wcv[tid] : -2.0f;
    int   ix = (tid < 40) ? wci[tid] : 0x7fffffff;
    for (int r = 0; r < TOPK; ++r) {
        float bv = v; int bi = ix;
#pragma unroll
        for (int off = 32; off >= 1; off >>= 1) {
            float ov = __shfl_xor(bv, off, 64);
            int   oi = __shfl_xor(bi, off, 64);
            if (better(ov, oi, bv, bi)) { bv = ov; bi = oi; }
        }
        if (v == bv && ix == bi) { v = -2.0f; ix = 0x7fffffff; }
        if (tid == 0) emit(r, bv, bi);
    }
}

// Exact IoU: bitwise-matches the numpy reference (verified absmax 0.0 in
// rounds 1-3). No FMA contraction (__fmul_rn), IEEE f32 divide. Used ONLY
// for candidate re-ranking (selection must be exact).
__device__ __forceinline__ float iou_exact(const float4 a, const float aA,
                                           const float4 b, const float bA) {
    const float ltx = fmaxf(a.x, b.x);
    const float lty = fmaxf(a.y, b.y);
    const float rbx = fminf(a.z, b.z);
    const float rby = fminf(a.w, b.w);
    const float w = fmaxf(rbx - ltx, 0.0f);
    const float h = fmaxf(rby - lty, 0.0f);
    const float inter = __fmul_rn(w, h);
    const float s = aA + bA;
    const float uni = s - inter;
    const float den = uni + 1e-8f;
    return inter / den;
}

// Fast IoU: v_rcp_f32 (rel err ~1e-7). Stored values only need the 2e-2
// harness tolerance; selection is re-derived exactly in the final kernel;
// SLACK=2e-5 covers all fast-vs-exact discrepancies in the threshold chain.
__device__ __forceinline__ float iou_fast(const float4 a, const float aA,
                                          const float4 b, const float bA) {
    const float ltx = fmaxf(a.x, b.x);
    const float lty = fmaxf(a.y, b.y);
    const float rbx = fminf(a.z, b.z);
    const float rby = fminf(a.w, b.w);
    const float w = fmaxf(rbx - ltx, 0.0f);
    const float h = fmaxf(rby - lty, 0.0f);
    const float inter = w * h;
    const float den = (aA + bA - inter) + 1e-8f;
    return inter * __builtin_amdgcn_rcpf(den);
}

// K0: sampled slot-max sketch. Each block: max of 256 fast-IoU samples ->
// atomicMax into slots[bid % 10]. Tm = min(slots) - SLACK is a valid lower
// bound on the global 10th-largest: the 10 slot maxima come from disjoint
// block partitions (10 distinct elements), and min of any 10 distinct
// elements <= 10th-largest. Slots pre-zeroed via hipMemsetAsync; IoU >= 0
// so float bits are monotonic under unsigned atomicMax.
__global__ __launch_bounds__(BLK) void sample_max_kernel(
    const float4* __restrict__ prop, const float4* __restrict__ gt,
    unsigned int* __restrict__ slots, int N, int M) {
    const int tid = threadIdx.x;
    const int bid = blockIdx.x;
    const int row = bid * ROWS_PER_BLOCK + (tid & 7);
    long long c = ((long long)(tid >> 3) * M) >> 5;
    const int col = (int)((c + (bid & 63)) % M);

    float v = 0.0f;
    if (row < N) {
        const float4 a = prop[row];
        const float aA = (a.z - a.x) * (a.w - a.y);
        const float4 b = gt[col];
        const float bA = (b.z - b.x) * (b.w - b.y);
        v = iou_fast(a, aA, b, bA);
    }

    __shared__ float sred[4];
#pragma unroll
    for (int off = 32; off >= 1; off >>= 1)
        v = fmaxf(v, __shfl_xor(v, off, 64));
    if ((tid & 63) == 0) sred[tid >> 6] = v;
    __syncthreads();
    if (tid == 0) {
        const float bm = fmaxf(fmaxf(sred[0], sred[1]), fmaxf(sred[2], sred[3]));
        atomicMax(&slots[bid % NSLOTS], __float_as_uint(bm));
    }
}

// K1: round-3 structure (best measured: interleaved iou+mask float4 stores,
// 4-col gather tiles, 8 rows/block) with rcp fast-IoU swapped in. Plain
// stores (nt regressed, round 4). Rows hoisted to registers (40 VGPR, no
// spill at ROWS=8 — the ROWS=16 variant spilled, round 6).
__global__ __launch_bounds__(BLK) void iou_main_kernel(
    const float4* __restrict__ prop, const float4* __restrict__ gt,
    float* __restrict__ iou_out, float* __restrict__ mask_out,
    const unsigned int* __restrict__ slots, int* __restrict__ cand_cnt,
    int* __restrict__ cand_idx, int N, int M) {
    const int tid = threadIdx.x;
    const int bid = blockIdx.x;
    const int row0 = bid * ROWS_PER_BLOCK;

    unsigned int mn = slots[0];
#pragma unroll
    for (int s = 1; s < NSLOTS; ++s) mn = min(mn, slots[s]);
    const float Tm = __uint_as_float(mn) - SLACK;

    float4 pa[ROWS_PER_BLOCK];
    float  paA[ROWS_PER_BLOCK];
#pragma unroll
    for (int nl = 0; nl < ROWS_PER_BLOCK; ++nl) {
        const int r = row0 + nl;
        const float4 a = (r < N) ? prop[r] : make_float4(0.f, 0.f, 0.f, 0.f);
        pa[nl] = a;
        paA[nl] = (a.z - a.x) * (a.w - a.y);
    }

    const f4vec zero4 = {0.0f, 0.0f, 0.0f, 0.0f};
    for (int m0 = 4 * tid; m0 < M; m0 += 4 * BLK) {    // M % 4 == 0
        const float4 b0 = gt[m0 + 0], b1 = gt[m0 + 1], b2 = gt[m0 + 2], b3 = gt[m0 + 3];
        const float bA0 = (b0.z - b0.x) * (b0.w - b0.y);
        const float bA1 = (b1.z - b1.x) * (b1.w - b1.y);
        const float bA2 = (b2.z - b2.x) * (b2.w - b2.y);
        const float bA3 = (b3.z - b3.x) * (b3.w - b3.y);
#pragma unroll
        for (int nl = 0; nl < ROWS_PER_BLOCK; ++nl) {
            const int row = row0 + nl;
            if (row < N) {
                const float i0 = iou_fast(pa[nl], paA[nl], b0, bA0);
                const float i1 = iou_fast(pa[nl], paA[nl], b1, bA1);
                const float i2 = iou_fast(pa[nl], paA[nl], b2, bA2);
                const float i3 = iou_fast(pa[nl], paA[nl], b3, bA3);
                const long long base = (long long)row * M + m0;
                const f4vec iv = {i0, i1, i2, i3};
                *reinterpret_cast<f4vec*>(iou_out + base) = iv;
                *reinterpret_cast<f4vec*>(mask_out + base) = zero4;
                const float mx = fmaxf(fmaxf(i0, i1), fmaxf(i2, i3));
                if (mx >= Tm) {                        // rare
                    if (i0 >= Tm) { int s = atomicAdd(cand_cnt, 1); if (s < CAND_CAP) cand_idx[s] = (int)base; }
                    if (i1 >= Tm) { int s = atomicAdd(cand_cnt, 1); if (s < CAND_CAP) cand_idx[s] = (int)base + 1; }
                    if (i2 >= Tm) { int s = atomicAdd(cand_cnt, 1); if (s < CAND_CAP) cand_idx[s] = (int)base + 2; }
                    if (i3 >= Tm) { int s = atomicAdd(cand_cnt, 1); if (s < CAND_CAP) cand_idx[s] = (int)base + 3; }
                }
            }
        }
    }
}

// K4: recompute EXACT IoU for each candidate from the raw boxes, rank by
// (exact value desc, index asc) — bitwise-identical selection to the
// reference regardless of what K1 stored. Scatter ones into mask.
__global__ __launch_bounds__(BLK) void final_kernel(
    const float4* __restrict__ prop, const float4* __restrict__ gt,
    const int* __restrict__ cand_cnt, const int* __restrict__ cand_idx,
    float* __restrict__ mask_out, int M) {
    __shared__ float wcv[4 * TOPK];
    __shared__ int   wci[4 * TOPK];
    const int tid = threadIdx.x;
    int c = *cand_cnt;
    if (c > CAND_CAP) c = CAND_CAP;

    float lv[TOPK]; int li[TOPK];
#pragma unroll
    for (int j = 0; j < TOPK; ++j) { lv[j] = -2.0f; li[j] = 0x7fffffff; }
    float mv = -2.0f; int mi = 0x7fffffff;

    for (int i = tid; i < c; i += BLK) {
        const int idx = cand_idx[i];
        const int row = idx / M;
        const int col = idx - row * M;
        const float4 a = prop[row];
        const float4 b = gt[col];
        const float aA = __fmul_rn(a.z - a.x, a.w - a.y);
        const float bA = __fmul_rn(b.z - b.x, b.w - b.y);
        const float v = iou_exact(a, aA, b, bA);
        if (better(v, idx, mv, mi)) insert10(lv, li, v, idx, mv, mi);
    }
    waveReduceTop10(lv, li, wcv, wci, tid);
    __syncthreads();
    if (tid < 64) {
        wave0FinalTop10(wcv, wci, tid, [&](int r, float bv, int bi) {
            (void)r;
            if (bi >= 0 && bi != 0x7fffffff && bv >= 0.0f) mask_out[bi] = 1.0f;
        });
    }
}

extern "C" void kernel_launch(void* const* d_in, const int* in_sizes, int n_in,
                              void* d_out, int out_size, void* d_ws, size_t ws_size,
                              hipStream_t stream) {
    const float4* prop = (const float4*)d_in[0];
    // d_in[1] = cls_prob (unused), d_in[3] = gt_cls (unused)
    const float4* gt = (const float4*)d_in[2];
    const int N = in_sizes[0] / 4;
    const int M = in_sizes[2] / 4;

    float* iou_out = (float*)d_out;
    float* mask_out = iou_out + (long long)N * M;

    // ws layout: slots[10] u32 @0 | cand_cnt @40 | cand_idx @64
    char* ws = (char*)d_ws;
    unsigned int* slots = (unsigned int*)ws;
    int* cand_cnt = (int*)(ws + 40);
    int* cand_idx = (int*)(ws + 64);

    hipMemsetAsync(ws, 0, 44, stream);   // zero slots + cand_cnt

    const int nblocks = (N + ROWS_PER_BLOCK - 1) / ROWS_PER_BLOCK;

    sample_max_kernel<<<nblocks, BLK, 0, stream>>>(prop, gt, slots, N, M);
    iou_main_kernel<<<nblocks, BLK, 0, stream>>>(prop, gt, iou_out, mask_out,
                                                 slots, cand_cnt, cand_idx, N, M);
    final_kernel<<<1, BLK, 0, stream>>>(prop, gt, cand_cnt, cand_idx, mask_out, M);
}

// Round 8
// 89.595 us; speedup vs baseline: 1.3619x; 1.1646x over previous
//
#include <hip/hip_runtime.h>

#define TOPK 10
#define BLK 256
#define ROWS_PER_BLOCK 8
#define CAND_CAP 32768
#define SLACK 2e-5f

typedef float f4vec __attribute__((ext_vector_type(4)));

__device__ __forceinline__ bool better(float v1, int i1, float v2, int i2) {
    // top_k order: larger value first; ties broken by smaller flat index
    return (v1 > v2) || (v1 == v2 && i1 < i2);
}

__device__ __forceinline__ void insert10(float (&lv)[TOPK], int (&li)[TOPK],
                                         float v, int ix, float& mv, int& mi) {
    int ws = 0; float wv = lv[0]; int wi = li[0];
#pragma unroll
    for (int j = 1; j < TOPK; ++j)
        if (better(wv, wi, lv[j], li[j])) { wv = lv[j]; wi = li[j]; ws = j; }
#pragma unroll
    for (int j = 0; j < TOPK; ++j)
        if (j == ws) { lv[j] = v; li[j] = ix; }
    mv = lv[0]; mi = li[0];
#pragma unroll
    for (int j = 1; j < TOPK; ++j)
        if (better(mv, mi, lv[j], li[j])) { mv = lv[j]; mi = li[j]; }
}

__device__ __forceinline__ void waveReduceTop10(float (&lv)[TOPK], int (&li)[TOPK],
                                                float* wcv, int* wci, int tid) {
    const int wave = tid >> 6;
    const int lane = tid & 63;
    for (int r = 0; r < TOPK; ++r) {
        float bv = lv[0]; int bi = li[0];
#pragma unroll
        for (int j = 1; j < TOPK; ++j)
            if (better(lv[j], li[j], bv, bi)) { bv = lv[j]; bi = li[j]; }
#pragma unroll
        for (int off = 32; off >= 1; off >>= 1) {
            float ov = __shfl_xor(bv, off, 64);
            int   oi = __shfl_xor(bi, off, 64);
            if (better(ov, oi, bv, bi)) { bv = ov; bi = oi; }
        }
#pragma unroll
        for (int j = 0; j < TOPK; ++j)
            if (lv[j] == bv && li[j] == bi) { lv[j] = -2.0f; li[j] = 0x7fffffff; }
        if (lane == 0) { wcv[wave * TOPK + r] = bv; wci[wave * TOPK + r] = bi; }
    }
}

template <typename EmitFn>
__device__ __forceinline__ void wave0FinalTop10(const float* wcv, const int* wci,
                                                int tid, EmitFn emit) {
    float v = (tid < 40) ? wcv[tid] : -2.0f;
    int   ix = (tid < 40) ? wci[tid] : 0x7fffffff;
    for (int r = 0; r < TOPK; ++r) {
        float bv = v; int bi = ix;
#pragma unroll
        for (int off = 32; off >= 1; off >>= 1) {
            float ov = __shfl_xor(bv, off, 64);
            int   oi = __shfl_xor(bi, off, 64);
            if (better(ov, oi, bv, bi)) { bv = ov; bi = oi; }
        }
        if (v == bv && ix == bi) { v = -2.0f; ix = 0x7fffffff; }
        if (tid == 0) emit(r, bv, bi);
    }
}

// Exact IoU: bitwise-matches the numpy reference (verified absmax 0.0 in
// rounds 1-3). No FMA contraction (__fmul_rn), IEEE f32 divide. Used ONLY
// for candidate re-ranking (selection must be exact).
__device__ __forceinline__ float iou_exact(const float4 a, const float aA,
                                           const float4 b, const float bA) {
    const float ltx = fmaxf(a.x, b.x);
    const float lty = fmaxf(a.y, b.y);
    const float rbx = fminf(a.z, b.z);
    const float rby = fminf(a.w, b.w);
    const float w = fmaxf(rbx - ltx, 0.0f);
    const float h = fmaxf(rby - lty, 0.0f);
    const float inter = __fmul_rn(w, h);
    const float s = aA + bA;
    const float uni = s - inter;
    const float den = uni + 1e-8f;
    return inter / den;
}

// Fast IoU: v_rcp_f32 (rel err ~1e-7). Stored values only need the 2e-2
// harness tolerance; selection is re-derived exactly in final_kernel;
// SLACK=2e-5 covers all fast-vs-exact discrepancies in the threshold chain.
__device__ __forceinline__ float iou_fast(const float4 a, const float aA,
                                          const float4 b, const float bA) {
    const float ltx = fmaxf(a.x, b.x);
    const float lty = fmaxf(a.y, b.y);
    const float rbx = fminf(a.z, b.z);
    const float rby = fminf(a.w, b.w);
    const float w = fmaxf(rbx - ltx, 0.0f);
    const float h = fmaxf(rby - lty, 0.0f);
    const float inter = w * h;
    const float den = (aA + bA - inter) + 1e-8f;
    return inter * __builtin_amdgcn_rcpf(den);
}

// K0: SAMPLED max-sketch (r3 structure verbatim). One fast-IoU sample per
// thread -> per-block max. The 10th-largest of these maxes (minus slack) is
// a valid lower bound on the global 10th-largest.
__global__ __launch_bounds__(BLK) void sample_max_kernel(
    const float4* __restrict__ prop, const float4* __restrict__ gt,
    float* __restrict__ blockmax, int N, int M) {
    const int tid = threadIdx.x;
    const int bid = blockIdx.x;
    const int row = bid * ROWS_PER_BLOCK + (tid & 7);
    long long c = ((long long)(tid >> 3) * M) >> 5;
    const int col = (int)((c + (bid & 63)) % M);

    float v = -2.0f;
    if (row < N) {
        const float4 a = prop[row];
        const float aA = (a.z - a.x) * (a.w - a.y);
        const float4 b = gt[col];
        const float bA = (b.z - b.x) * (b.w - b.y);
        v = iou_fast(a, aA, b, bA);
    }

    __shared__ float sred[4];
#pragma unroll
    for (int off = 32; off >= 1; off >>= 1)
        v = fmaxf(v, __shfl_xor(v, off, 64));
    if ((tid & 63) == 0) sred[tid >> 6] = v;
    __syncthreads();
    if (tid == 0)
        blockmax[bid] = fmaxf(fmaxf(sred[0], sred[1]), fmaxf(sred[2], sred[3]));
}

// K2: T = (10th largest sampled block max) - SLACK; zero candidate counter.
__global__ __launch_bounds__(BLK) void threshold_kernel(
    const float* __restrict__ blockmax, int nb,
    float* __restrict__ tm_ptr, int* __restrict__ cand_cnt) {
    __shared__ float wcv[4 * TOPK];
    __shared__ int   wci[4 * TOPK];
    const int tid = threadIdx.x;

    float lv[TOPK]; int li[TOPK];
#pragma unroll
    for (int j = 0; j < TOPK; ++j) { lv[j] = -2.0f; li[j] = 0x7fffffff; }
    float mv = -2.0f; int mi = 0x7fffffff;

    for (int i = tid; i < nb; i += BLK) {
        const float v = blockmax[i];
        if (better(v, i, mv, mi)) insert10(lv, li, v, i, mv, mi);
    }
    waveReduceTop10(lv, li, wcv, wci, tid);
    __syncthreads();
    if (tid < 64) {
        wave0FinalTop10(wcv, wci, tid, [&](int r, float bv, int bi) {
            (void)bi;
            if (r == TOPK - 1) *tm_ptr = bv - SLACK;
        });
    }
    if (tid == 0) *cand_cnt = 0;
}

// K1: round-3 body VERBATIM except iou_exact -> iou_fast, plus
// __launch_bounds__(BLK, 4) to pin >=4 waves/SIMD (VGPR <= 128).
// No manual hoisting: prop[row] has a block-uniform address -> compiler
// emits s_load into SGPRs (r7's VGPR hoist regressed -17 us).
__global__ __launch_bounds__(BLK, 4) void iou_main_kernel(
    const float4* __restrict__ prop, const float4* __restrict__ gt,
    float* __restrict__ iou_out, float* __restrict__ mask_out,
    const float* __restrict__ tm_ptr, int* __restrict__ cand_cnt,
    int* __restrict__ cand_idx, int N, int M) {
    const int tid = threadIdx.x;
    const int bid = blockIdx.x;
    const int row0 = bid * ROWS_PER_BLOCK;
    const float Tm = *tm_ptr;
    const int M4 = M & ~3;
    const f4vec zero4 = {0.0f, 0.0f, 0.0f, 0.0f};

    for (int m0 = 4 * tid; m0 < M4; m0 += 4 * BLK) {
        const float4 b0 = gt[m0 + 0], b1 = gt[m0 + 1], b2 = gt[m0 + 2], b3 = gt[m0 + 3];
        const float bA0 = (b0.z - b0.x) * (b0.w - b0.y);
        const float bA1 = (b1.z - b1.x) * (b1.w - b1.y);
        const float bA2 = (b2.z - b2.x) * (b2.w - b2.y);
        const float bA3 = (b3.z - b3.x) * (b3.w - b3.y);
#pragma unroll
        for (int nl = 0; nl < ROWS_PER_BLOCK; ++nl) {
            const int row = row0 + nl;
            if (row < N) {
                const float4 a = prop[row];                 // uniform -> SGPR
                const float aA = (a.z - a.x) * (a.w - a.y);
                const float i0 = iou_fast(a, aA, b0, bA0);
                const float i1 = iou_fast(a, aA, b1, bA1);
                const float i2 = iou_fast(a, aA, b2, bA2);
                const float i3 = iou_fast(a, aA, b3, bA3);
                const long long base = (long long)row * M + m0;
                const f4vec iv = {i0, i1, i2, i3};
                *reinterpret_cast<f4vec*>(iou_out + base) = iv;
                *reinterpret_cast<f4vec*>(mask_out + base) = zero4;
                if (i0 >= Tm || i1 >= Tm || i2 >= Tm || i3 >= Tm) {  // rare
                    if (i0 >= Tm) { int s = atomicAdd(cand_cnt, 1); if (s < CAND_CAP) cand_idx[s] = (int)base; }
                    if (i1 >= Tm) { int s = atomicAdd(cand_cnt, 1); if (s < CAND_CAP) cand_idx[s] = (int)base + 1; }
                    if (i2 >= Tm) { int s = atomicAdd(cand_cnt, 1); if (s < CAND_CAP) cand_idx[s] = (int)base + 2; }
                    if (i3 >= Tm) { int s = atomicAdd(cand_cnt, 1); if (s < CAND_CAP) cand_idx[s] = (int)base + 3; }
                }
            }
        }
    }
}

// K4: recompute EXACT IoU for each candidate from the raw boxes, rank by
// (exact value desc, index asc) — bitwise-identical selection to the
// reference regardless of what K1 stored. Scatter ones into mask.
__global__ __launch_bounds__(BLK) void final_kernel(
    const float4* __restrict__ prop, const float4* __restrict__ gt,
    const int* __restrict__ cand_cnt, const int* __restrict__ cand_idx,
    float* __restrict__ mask_out, int M) {
    __shared__ float wcv[4 * TOPK];
    __shared__ int   wci[4 * TOPK];
    const int tid = threadIdx.x;
    int c = *cand_cnt;
    if (c > CAND_CAP) c = CAND_CAP;

    float lv[TOPK]; int li[TOPK];
#pragma unroll
    for (int j = 0; j < TOPK; ++j) { lv[j] = -2.0f; li[j] = 0x7fffffff; }
    float mv = -2.0f; int mi = 0x7fffffff;

    for (int i = tid; i < c; i += BLK) {
        const int idx = cand_idx[i];
        const int row = idx / M;
        const int col = idx - row * M;
        const float4 a = prop[row];
        const float4 b = gt[col];
        const float aA = __fmul_rn(a.z - a.x, a.w - a.y);
        const float bA = __fmul_rn(b.z - b.x, b.w - b.y);
        const float v = iou_exact(a, aA, b, bA);
        if (better(v, idx, mv, mi)) insert10(lv, li, v, idx, mv, mi);
    }
    waveReduceTop10(lv, li, wcv, wci, tid);
    __syncthreads();
    if (tid < 64) {
        wave0FinalTop10(wcv, wci, tid, [&](int r, float bv, int bi) {
            (void)r;
            if (bi >= 0 && bi != 0x7fffffff && bv >= 0.0f) mask_out[bi] = 1.0f;
        });
    }
}

extern "C" void kernel_launch(void* const* d_in, const int* in_sizes, int n_in,
                              void* d_out, int out_size, void* d_ws, size_t ws_size,
                              hipStream_t stream) {
    const float4* prop = (const float4*)d_in[0];
    // d_in[1] = cls_prob (unused), d_in[3] = gt_cls (unused)
    const float4* gt = (const float4*)d_in[2];
    const int N = in_sizes[0] / 4;
    const int M = in_sizes[2] / 4;

    float* iou_out = (float*)d_out;
    float* mask_out = iou_out + (long long)N * M;

    const int nblocks = (N + ROWS_PER_BLOCK - 1) / ROWS_PER_BLOCK;

    // ws layout: blockmax[nblocks] @0 | Tm @16K | cnt @16K+4 | cand @16K+8
    char* ws = (char*)d_ws;
    float* blockmax = (float*)ws;
    float* tm_ptr = (float*)(ws + 16384);
    int* cand_cnt = (int*)(ws + 16388);
    int* cand_idx = (int*)(ws + 16392);

    sample_max_kernel<<<nblocks, BLK, 0, stream>>>(prop, gt, blockmax, N, M);
    threshold_kernel<<<1, BLK, 0, stream>>>(blockmax, nblocks, tm_ptr, cand_cnt);
    iou_main_kernel<<<nblocks, BLK, 0, stream>>>(prop, gt, iou_out, mask_out,
                                                 tm_ptr, cand_cnt, cand_idx, N, M);
    final_kernel<<<1, BLK, 0, stream>>>(prop, gt, cand_cnt, cand_idx, mask_out, M);
}